// Round 1
// 99.778 us; speedup vs baseline: 1.0675x; 1.0675x over previous
//
#include <hip/hip_runtime.h>
#include <hip/hip_fp16.h>
#include <stdint.h>

#define D0 1024
#define D1 8192
#define D2 8192
#define D3 10240
#define B_ROWS 4096

// LDS layout (bytes), 8 rows/block fp16 row-interleaved [gate][8 rows]=16B:
// xb 16K | h2 128K | csum 320 -> 144.3 KB, 1 block/CU (wave-capped anyway at
// 1024 thr; trades waves 32->16 for half the sequential blocks per CU).
#define SM_XB     0
#define SM_H2     16384
#define SM_CSUM   (16384 + 131072)
#define SM_BYTES  (16384 + 131072 + 320)

// softmax(w[16]) @ OP_COEF -> (c0,c1,c2,c3)
__device__ __forceinline__ float4 softmax_coef(const float* __restrict__ w) {
    const float4* wv = (const float4*)w;
    float4 q0 = wv[0], q1 = wv[1], q2 = wv[2], q3 = wv[3];
    float wa[16] = {q0.x, q0.y, q0.z, q0.w, q1.x, q1.y, q1.z, q1.w,
                    q2.x, q2.y, q2.z, q2.w, q3.x, q3.y, q3.z, q3.w};
    float m = wa[0];
#pragma unroll
    for (int i = 1; i < 16; ++i) m = fmaxf(m, wa[i]);
    float e[16], s = 0.f;
#pragma unroll
    for (int i = 0; i < 16; ++i) { e[i] = __expf(wa[i] - m); s += e[i]; }
    float inv = 1.f / s;
    static constexpr float OPC[16][4] = {
        {0.f, 0.f, 0.f, 0.f}, {0.f, 0.f, 0.f, 1.f}, {0.f, 1.f, 0.f, -1.f}, {0.f, 1.f, 0.f, 0.f},
        {0.f, 0.f, 1.f, -1.f}, {0.f, 0.f, 1.f, 0.f}, {0.f, 1.f, 1.f, -2.f}, {0.f, 1.f, 1.f, -1.f},
        {1.f, -1.f, -1.f, 1.f}, {1.f, -1.f, -1.f, 2.f}, {1.f, 0.f, -1.f, 0.f}, {1.f, 0.f, -1.f, 1.f},
        {1.f, -1.f, 0.f, 0.f}, {1.f, -1.f, 0.f, 1.f}, {1.f, 0.f, 0.f, -1.f}, {1.f, 0.f, 0.f, 0.f}};
    float c0 = 0.f, c1 = 0.f, c2 = 0.f, c3 = 0.f;
#pragma unroll
    for (int i = 0; i < 16; ++i) {  // 0/±1/±2 multiplies fold at compile time
        float p = e[i] * inv;
        c0 += p * OPC[i][0];
        c1 += p * OPC[i][1];
        c2 += p * OPC[i][2];
        c3 += p * OPC[i][3];
    }
    return make_float4(c0, c1, c2, c3);
}

__device__ __forceinline__ uint2 pack_coef(float4 c) {
    uint2 r;
    r.x = __builtin_bit_cast(uint32_t, __floats2half2_rn(c.x, c.y));
    r.y = __builtin_bit_cast(uint32_t, __floats2half2_rn(c.z, c.w));
    return r;
}

// prep: run-invariant metadata, packed for dwordx4 consumption.
//  bcM1[g] = (xiA, xiB, coO.lo, coO.hi)  xi* = packed x BYTE offsets (<<4,
//  bcM2[g] = (cA.lo, cA.hi, cB.lo, cB.hi) fits u16: max 1023*16)
//  d3M[g]  = (ei, co.lo, co.hi, 0)       ei = packed h2 ELEMENT indices
//
// v2: one thread per SOFTMAX (not per gate). The 3 softmaxes of a D2 gate
// are independent: role O (outer coefs + x byte offsets -> bcM1[g]),
// role A (-> bcM2[g].xy), role B (-> bcM2[g].zw). 3x parallelism, 1/3 the
// serial dependent-load+exp chain per thread. Blocks are role-uniform
// (8192 % 256 == 0).
#define PREP_TOTAL (3 * D2 + D3)
__global__ __launch_bounds__(256) void prep_kernel(
    const float* __restrict__ w1, const float* __restrict__ w2,
    const float* __restrict__ w3,
    const int* __restrict__ ia1, const int* __restrict__ ib1,
    const int* __restrict__ ia2, const int* __restrict__ ib2,
    const int* __restrict__ ia3, const int* __restrict__ ib3,
    uint4* __restrict__ bcM1, uint4* __restrict__ bcM2,
    uint4* __restrict__ d3M) {
    int G = blockIdx.x * 256 + threadIdx.x;
    if (G < D2) {  // role O
        int g = G;
        int pa = ia2[g], pb = ib2[g];
        float4 cO = softmax_coef(w2 + (size_t)g * 16);
        uint32_t xiA = (uint32_t)(ia1[pa] << 4) | ((uint32_t)(ib1[pa] << 4) << 16);
        uint32_t xiB = (uint32_t)(ia1[pb] << 4) | ((uint32_t)(ib1[pb] << 4) << 16);
        uint2 o = pack_coef(cO);
        bcM1[g] = make_uint4(xiA, xiB, o.x, o.y);
    } else if (G < 2 * D2) {  // role A
        int g = G - D2;
        int pa = ia2[g];
        uint2 a = pack_coef(softmax_coef(w1 + (size_t)pa * 16));
        ((uint2*)bcM2)[2 * g] = a;
    } else if (G < 3 * D2) {  // role B
        int g = G - 2 * D2;
        int pb = ib2[g];
        uint2 b = pack_coef(softmax_coef(w1 + (size_t)pb * 16));
        ((uint2*)bcM2)[2 * g + 1] = b;
    } else {  // layer-3 gate
        int g = G - 3 * D2;
        float4 cO = softmax_coef(w3 + (size_t)g * 16);
        uint2 o = pack_coef(cO);
        uint32_t ei = (uint32_t)ia3[g] | ((uint32_t)ib3[g] << 16);
        d3M[g] = make_uint4(ei, o.x, o.y, 0u);
    }
}

// One gate for 8 rows (4x half2); compact coefs (c0c1, c2c3) broadcast here.
// h = (c0 + c2*b) + a*(c1 + c3*b): 12 v_pk_fma_f16 + 4 extracts.
__device__ __forceinline__ uint4 gate8(uint4 av, uint4 bv, uint2 cf) {
    __half2 p = __builtin_bit_cast(__half2, cf.x);  // (c0,c1)
    __half2 q = __builtin_bit_cast(__half2, cf.y);  // (c2,c3)
    __half2 c0 = __low2half2(p), c1 = __high2half2(p);
    __half2 c2 = __low2half2(q), c3 = __high2half2(q);
    uint4 r;
#pragma unroll
    for (int i = 0; i < 4; ++i) {
        __half2 a = __builtin_bit_cast(__half2, (&av.x)[i]);
        __half2 b = __builtin_bit_cast(__half2, (&bv.x)[i]);
        __half2 h = __hfma2(a, __hfma2(b, c3, c1), __hfma2(b, c2, c0));
        (&r.x)[i] = __builtin_bit_cast(uint32_t, h);
    }
    return r;
}

// Full-wave f32 sum on the VALU pipe via DPP (row_shr 1/2/4/8 +
// row_bcast 15/31); result valid in lane 63. Replaces the __shfl_xor
// butterfly, which lowers to ds_swizzle and competes with the stage-D
// gathers for the single per-CU LDS pipe.
__device__ __forceinline__ float dpp_sum_f32(float x) {
#define DPPADD(ctrl, rmask)                                              \
    x += __builtin_bit_cast(float, __builtin_amdgcn_update_dpp(          \
             0, __builtin_bit_cast(int, x), (ctrl), (rmask), 0xf, true))
    DPPADD(0x111, 0xf);  // row_shr:1
    DPPADD(0x112, 0xf);  // row_shr:2
    DPPADD(0x114, 0xf);  // row_shr:4
    DPPADD(0x118, 0xf);  // row_shr:8  -> lane15 of each row = row sum
    DPPADD(0x142, 0xa);  // row_bcast:15 into rows 1,3
    DPPADD(0x143, 0xc);  // row_bcast:31 into rows 2,3 -> lane63 = total
#undef DPPADD
    return x;
}

// Fused: layers 1+2 fused, then layer 3 + group-sum. One block = 8 rows,
// activations [gate][8 rows] fp16 (16 B) -> every gather is one
// ds_read_b128. Half the blocks of the 4-row shape: half the per-CU
// barrier/stage-A/tail overhead and ~20% fewer LDS cycles per row.
__global__ __launch_bounds__(1024, 4) void fused_kernel(
    const float* __restrict__ x, const uint4* __restrict__ bcM1,
    const uint4* __restrict__ bcM2, const uint4* __restrict__ d3M,
    float* __restrict__ out) {
    extern __shared__ char sm[];
    uint4* xb = (uint4*)(sm + SM_XB);
    float* csum = (float*)(sm + SM_CSUM);

    const int t = threadIdx.x;
    const int rowbase = blockIdx.x << 3;  // 8 rows per block
    const int tg = t << 1;  // first gate of this thread's pair

    // Preload iter-0 index metadata (latency hidden behind stage A + barrier).
    uint4 m1a_n = bcM1[tg];
    uint4 m1b_n = bcM1[tg + 1];

    // Stage A: 8 rows of x -> fp16, row-interleaved into xb (16 B/gate).
    {
        const float* xp = x + (size_t)rowbase * D0 + t;
        uint4 v;
#pragma unroll
        for (int i = 0; i < 4; ++i) {
            float va = xp[(size_t)(2 * i) * D0];
            float vb = xp[(size_t)(2 * i + 1) * D0];
            (&v.x)[i] = __builtin_bit_cast(uint32_t, __floats2half2_rn(va, vb));
        }
        xb[t] = v;
    }
    if (t < 80) csum[t] = 0.f;
    __syncthreads();

    // Stage BC: fused layers 1+2, 2 gates/thread/iter, 4 iters covers 8192.
#pragma unroll
    for (int k = 0; k < 4; ++k) {
        uint4 m1a = m1a_n, m1b = m1b_n;
        int g = tg + (k << 11);
        uint4 m2a = bcM2[g];
        uint4 m2b = bcM2[g + 1];
        if (k < 3) {  // depth-2 prefetch of the gather-address stream
            int gn = tg + ((k + 1) << 11);
            m1a_n = bcM1[gn];
            m1b_n = bcM1[gn + 1];
        }
        // 8 independent b128 gathers in flight.
        uint4 aa0 = *(const uint4*)(sm + (m1a.x & 0xffffu));
        uint4 ab0 = *(const uint4*)(sm + (m1a.x >> 16));
        uint4 ba0 = *(const uint4*)(sm + (m1a.y & 0xffffu));
        uint4 bb0 = *(const uint4*)(sm + (m1a.y >> 16));
        uint4 aa1 = *(const uint4*)(sm + (m1b.x & 0xffffu));
        uint4 ab1 = *(const uint4*)(sm + (m1b.x >> 16));
        uint4 ba1 = *(const uint4*)(sm + (m1b.y & 0xffffu));
        uint4 bb1 = *(const uint4*)(sm + (m1b.y >> 16));
        uint4 h0 = gate8(gate8(aa0, ab0, make_uint2(m2a.x, m2a.y)),
                         gate8(ba0, bb0, make_uint2(m2a.z, m2a.w)),
                         make_uint2(m1a.z, m1a.w));
        uint4 h1v = gate8(gate8(aa1, ab1, make_uint2(m2b.x, m2b.y)),
                          gate8(ba1, bb1, make_uint2(m2b.z, m2b.w)),
                          make_uint2(m1b.z, m1b.w));
        *(uint4*)(sm + SM_H2 + ((uint32_t)g << 4)) = h0;
        *(uint4*)(sm + SM_H2 + ((uint32_t)(g + 1) << 4)) = h1v;
    }
    __syncthreads();

    // Stage D: layer 3 + grouped sum, 2 gates/lane/iter, 5 iters x 128 gates.
    // Each 128-gate chunk lies entirely within one class (128 | 1024).
    {
        const int wv = t >> 6, lane = t & 63;
        const int gbase = wv * 640;
        const int cA = gbase >> 10;
        const int bnd = (cA + 1) << 10;
        const bool cross = (gbase + 640 > bnd);  // wave-uniform
        float s0[8] = {0.f, 0.f, 0.f, 0.f, 0.f, 0.f, 0.f, 0.f};
        float s1[8] = {0.f, 0.f, 0.f, 0.f, 0.f, 0.f, 0.f, 0.f};
#pragma unroll
        for (int j = 0; j < 5; ++j) {
            int gc = gbase + (j << 7);
            int g = gc + (lane << 1);
            uint4 ma = d3M[g];
            uint4 mb = d3M[g + 1];
            uint4 av0 = *(const uint4*)(sm + SM_H2 + ((ma.x & 0xffffu) << 4));
            uint4 bv0 = *(const uint4*)(sm + SM_H2 + ((ma.x >> 16) << 4));
            uint4 av1 = *(const uint4*)(sm + SM_H2 + ((mb.x & 0xffffu) << 4));
            uint4 bv1 = *(const uint4*)(sm + SM_H2 + ((mb.x >> 16) << 4));
            uint4 h0 = gate8(av0, bv0, make_uint2(ma.y, ma.z));
            uint4 h1v = gate8(av1, bv1, make_uint2(mb.y, mb.z));
            // Static-index accumulate (no runtime-selected pointer into
            // register arrays -> no scratch risk); branch is wave-uniform
            // per unrolled j.
            float pr8[8];
#pragma unroll
            for (int i = 0; i < 4; ++i) {
                __half2 pr = __hadd2(__builtin_bit_cast(__half2, (&h0.x)[i]),
                                     __builtin_bit_cast(__half2, (&h1v.x)[i]));
                pr8[2 * i] = __low2float(pr);
                pr8[2 * i + 1] = __high2float(pr);
            }
            if (gc < bnd) {
#pragma unroll
                for (int r = 0; r < 8; ++r) s0[r] += pr8[r];
            } else {
#pragma unroll
                for (int r = 0; r < 8; ++r) s1[r] += pr8[r];
            }
        }
        // Wave reduction on the VALU pipe (DPP), result in lane 63.
#pragma unroll
        for (int r = 0; r < 8; ++r) s0[r] = dpp_sum_f32(s0[r]);
        if (cross) {
#pragma unroll
            for (int r = 0; r < 8; ++r) s1[r] = dpp_sum_f32(s1[r]);
        }
        if (lane == 63) {
#pragma unroll
            for (int r = 0; r < 8; ++r) atomicAdd(&csum[cA * 8 + r], s0[r]);
            if (cross) {
#pragma unroll
                for (int r = 0; r < 8; ++r) atomicAdd(&csum[(cA + 1) * 8 + r], s1[r]);
            }
        }
    }
    __syncthreads();

    if (t < 80) {
        int c = t >> 3, r = t & 7;
        out[(size_t)(rowbase + r) * 10 + c] = csum[t] * (1.0f / 30.0f);
    }
}

extern "C" void kernel_launch(void* const* d_in, const int* in_sizes, int n_in,
                              void* d_out, int out_size, void* d_ws, size_t ws_size,
                              hipStream_t stream) {
    const float* x = (const float*)d_in[0];
    const float* w1 = (const float*)d_in[1];
    const float* w2 = (const float*)d_in[2];
    const float* w3 = (const float*)d_in[3];
    const int* ia1 = (const int*)d_in[4];
    const int* ib1 = (const int*)d_in[5];
    const int* ia2 = (const int*)d_in[6];
    const int* ib2 = (const int*)d_in[7];
    const int* ia3 = (const int*)d_in[8];
    const int* ib3 = (const int*)d_in[9];
    float* out = (float*)d_out;

    // Workspace: bcM1 128K | bcM2 128K | d3M 160K (all 16B-aligned).
    char* p = (char*)d_ws;
    uint4* bcM1 = (uint4*)p;    p += (size_t)D2 * 16;
    uint4* bcM2 = (uint4*)p;    p += (size_t)D2 * 16;
    uint4* d3M = (uint4*)p;

    // >64KB dynamic LDS opt-in (host-side; graph-capture safe). 144.3 KB
    // fits the 160 KB/CU pool.
    hipFuncSetAttribute(reinterpret_cast<const void*>(fused_kernel),
                        hipFuncAttributeMaxDynamicSharedMemorySize, SM_BYTES);

    prep_kernel<<<PREP_TOTAL / 256, 256, 0, stream>>>(
        w1, w2, w3, ia1, ib1, ia2, ib2, ia3, ib3, bcM1, bcM2, d3M);
    fused_kernel<<<B_ROWS / 8, 1024, SM_BYTES, stream>>>(x, bcM1, bcM2, d3M, out);
}

// Round 2
// 98.922 us; speedup vs baseline: 1.0767x; 1.0087x over previous
//
#include <hip/hip_runtime.h>
#include <hip/hip_fp16.h>
#include <stdint.h>

#define D0 1024
#define D1 8192
#define D2 8192
#define D3 10240
#define B_ROWS 4096

// LDS layout (bytes), 8 rows fp16 row-interleaved [gate][8 rows]=16B:
// xb 16K | h2 128K | csum 320 -> 144.3 KB, 1 block/CU (wave-capped anyway at
// 1024 thr). One block now covers 16 rows in two pipelined 8-row passes.
#define SM_XB     0
#define SM_H2     16384
#define SM_CSUM   (16384 + 131072)
#define SM_BYTES  (16384 + 131072 + 320)

// softmax(w[16]) @ OP_COEF -> (c0,c1,c2,c3)
__device__ __forceinline__ float4 softmax_coef(const float* __restrict__ w) {
    const float4* wv = (const float4*)w;
    float4 q0 = wv[0], q1 = wv[1], q2 = wv[2], q3 = wv[3];
    float wa[16] = {q0.x, q0.y, q0.z, q0.w, q1.x, q1.y, q1.z, q1.w,
                    q2.x, q2.y, q2.z, q2.w, q3.x, q3.y, q3.z, q3.w};
    float m = wa[0];
#pragma unroll
    for (int i = 1; i < 16; ++i) m = fmaxf(m, wa[i]);
    float e[16], s = 0.f;
#pragma unroll
    for (int i = 0; i < 16; ++i) { e[i] = __expf(wa[i] - m); s += e[i]; }
    float inv = 1.f / s;
    static constexpr float OPC[16][4] = {
        {0.f, 0.f, 0.f, 0.f}, {0.f, 0.f, 0.f, 1.f}, {0.f, 1.f, 0.f, -1.f}, {0.f, 1.f, 0.f, 0.f},
        {0.f, 0.f, 1.f, -1.f}, {0.f, 0.f, 1.f, 0.f}, {0.f, 1.f, 1.f, -2.f}, {0.f, 1.f, 1.f, -1.f},
        {1.f, -1.f, -1.f, 1.f}, {1.f, -1.f, -1.f, 2.f}, {1.f, 0.f, -1.f, 0.f}, {1.f, 0.f, -1.f, 1.f},
        {1.f, -1.f, 0.f, 0.f}, {1.f, -1.f, 0.f, 1.f}, {1.f, 0.f, 0.f, -1.f}, {1.f, 0.f, 0.f, 0.f}};
    float c0 = 0.f, c1 = 0.f, c2 = 0.f, c3 = 0.f;
#pragma unroll
    for (int i = 0; i < 16; ++i) {  // 0/±1/±2 multiplies fold at compile time
        float p = e[i] * inv;
        c0 += p * OPC[i][0];
        c1 += p * OPC[i][1];
        c2 += p * OPC[i][2];
        c3 += p * OPC[i][3];
    }
    return make_float4(c0, c1, c2, c3);
}

__device__ __forceinline__ uint2 pack_coef(float4 c) {
    uint2 r;
    r.x = __builtin_bit_cast(uint32_t, __floats2half2_rn(c.x, c.y));
    r.y = __builtin_bit_cast(uint32_t, __floats2half2_rn(c.z, c.w));
    return r;
}

// prep: run-invariant metadata, packed for dwordx4 consumption.
//  bcM1[g] = (xiA, xiB, coO.lo, coO.hi)  xi* = packed x BYTE offsets
//  bcM2[g] = (cA.lo, cA.hi, cB.lo, cB.hi)
//  d3M[g]  = (ei, co.lo, co.hi, 0)       ei = packed h2 ELEMENT indices
// One thread per SOFTMAX: roles O/A/B write disjoint parts (3x parallelism,
// 1/3 the serial dependent-load+exp chain per thread).
#define PREP_TOTAL (3 * D2 + D3)
__global__ __launch_bounds__(256) void prep_kernel(
    const float* __restrict__ w1, const float* __restrict__ w2,
    const float* __restrict__ w3,
    const int* __restrict__ ia1, const int* __restrict__ ib1,
    const int* __restrict__ ia2, const int* __restrict__ ib2,
    const int* __restrict__ ia3, const int* __restrict__ ib3,
    uint4* __restrict__ bcM1, uint4* __restrict__ bcM2,
    uint4* __restrict__ d3M) {
    int G = blockIdx.x * 256 + threadIdx.x;
    if (G < D2) {  // role O
        int g = G;
        int pa = ia2[g], pb = ib2[g];
        float4 cO = softmax_coef(w2 + (size_t)g * 16);
        uint32_t xiA = (uint32_t)(ia1[pa] << 4) | ((uint32_t)(ib1[pa] << 4) << 16);
        uint32_t xiB = (uint32_t)(ia1[pb] << 4) | ((uint32_t)(ib1[pb] << 4) << 16);
        uint2 o = pack_coef(cO);
        bcM1[g] = make_uint4(xiA, xiB, o.x, o.y);
    } else if (G < 2 * D2) {  // role A
        int g = G - D2;
        int pa = ia2[g];
        uint2 a = pack_coef(softmax_coef(w1 + (size_t)pa * 16));
        ((uint2*)bcM2)[2 * g] = a;
    } else if (G < 3 * D2) {  // role B
        int g = G - 2 * D2;
        int pb = ib2[g];
        uint2 b = pack_coef(softmax_coef(w1 + (size_t)pb * 16));
        ((uint2*)bcM2)[2 * g + 1] = b;
    } else {  // layer-3 gate
        int g = G - 3 * D2;
        float4 cO = softmax_coef(w3 + (size_t)g * 16);
        uint2 o = pack_coef(cO);
        uint32_t ei = (uint32_t)ia3[g] | ((uint32_t)ib3[g] << 16);
        d3M[g] = make_uint4(ei, o.x, o.y, 0u);
    }
}

// One gate for 8 rows (4x half2); compact coefs (c0c1, c2c3) broadcast here.
// h = (c0 + c2*b) + a*(c1 + c3*b): 12 v_pk_fma_f16 + 4 extracts.
__device__ __forceinline__ uint4 gate8(uint4 av, uint4 bv, uint2 cf) {
    __half2 p = __builtin_bit_cast(__half2, cf.x);  // (c0,c1)
    __half2 q = __builtin_bit_cast(__half2, cf.y);  // (c2,c3)
    __half2 c0 = __low2half2(p), c1 = __high2half2(p);
    __half2 c2 = __low2half2(q), c3 = __high2half2(q);
    uint4 r;
#pragma unroll
    for (int i = 0; i < 4; ++i) {
        __half2 a = __builtin_bit_cast(__half2, (&av.x)[i]);
        __half2 b = __builtin_bit_cast(__half2, (&bv.x)[i]);
        __half2 h = __hfma2(a, __hfma2(b, c3, c1), __hfma2(b, c2, c0));
        (&r.x)[i] = __builtin_bit_cast(uint32_t, h);
    }
    return r;
}

// Full-wave f32 sum on the VALU pipe via DPP (row_shr 1/2/4/8 +
// row_bcast 15/31); result valid in lane 63. Keeps the reduction off the
// LDS pipe, which is the kernel's bottleneck resource.
__device__ __forceinline__ float dpp_sum_f32(float x) {
#define DPPADD(ctrl, rmask)                                              \
    x += __builtin_bit_cast(float, __builtin_amdgcn_update_dpp(          \
             0, __builtin_bit_cast(int, x), (ctrl), (rmask), 0xf, true))
    DPPADD(0x111, 0xf);  // row_shr:1
    DPPADD(0x112, 0xf);  // row_shr:2
    DPPADD(0x114, 0xf);  // row_shr:4
    DPPADD(0x118, 0xf);  // row_shr:8  -> lane15 of each row = row sum
    DPPADD(0x142, 0xa);  // row_bcast:15 into rows 1,3
    DPPADD(0x143, 0xc);  // row_bcast:31 into rows 2,3 -> lane63 = total
#undef DPPADD
    return x;
}

// Stage BC body for one 8-row pass: fused layers 1+2.
// Gate map: thread t, iter k handles gates t + 2048k and t + 2048k + 1024.
// -> h2 writes are lane-LINEAR (conflict-free, vs 2-way bank-group conflict
//    of the old 2t/2t+1 map) and all metadata loads are 16B/lane coalesced.
__device__ __forceinline__ void stage_bc(char* sm, int t,
                                         const uint4* __restrict__ bcM1,
                                         const uint4* __restrict__ bcM2,
                                         uint4 m1a_n, uint4 m1b_n) {
#pragma unroll
    for (int k = 0; k < 4; ++k) {
        uint4 m1a = m1a_n, m1b = m1b_n;
        int g0 = t + (k << 11);       // + 2048k
        int g1 = g0 + 1024;
        uint4 m2a = bcM2[g0];
        uint4 m2b = bcM2[g1];
        if (k < 3) {  // depth-2 prefetch of the gather-address stream
            m1a_n = bcM1[g0 + 2048];
            m1b_n = bcM1[g1 + 2048];
        }
        // 8 independent b128 gathers in flight.
        uint4 aa0 = *(const uint4*)(sm + (m1a.x & 0xffffu));
        uint4 ab0 = *(const uint4*)(sm + (m1a.x >> 16));
        uint4 ba0 = *(const uint4*)(sm + (m1a.y & 0xffffu));
        uint4 bb0 = *(const uint4*)(sm + (m1a.y >> 16));
        uint4 aa1 = *(const uint4*)(sm + (m1b.x & 0xffffu));
        uint4 ab1 = *(const uint4*)(sm + (m1b.x >> 16));
        uint4 ba1 = *(const uint4*)(sm + (m1b.y & 0xffffu));
        uint4 bb1 = *(const uint4*)(sm + (m1b.y >> 16));
        uint4 h0 = gate8(gate8(aa0, ab0, make_uint2(m2a.x, m2a.y)),
                         gate8(ba0, bb0, make_uint2(m2a.z, m2a.w)),
                         make_uint2(m1a.z, m1a.w));
        uint4 h1v = gate8(gate8(aa1, ab1, make_uint2(m2b.x, m2b.y)),
                          gate8(ba1, bb1, make_uint2(m2b.z, m2b.w)),
                          make_uint2(m1b.z, m1b.w));
        *(uint4*)(sm + SM_H2 + ((uint32_t)g0 << 4)) = h0;
        *(uint4*)(sm + SM_H2 + ((uint32_t)g1 << 4)) = h1v;
    }
}

// Stage D body: layer 3 + grouped sum into csum (atomics from lane 63).
// Lane map per 128-gate chunk: gc+lane and gc+64+lane (coalesced d3M loads,
// sum-invariant: chunk lies in one class, 128 | 1024).
__device__ __forceinline__ void stage_d(char* sm, int t,
                                        const uint4* __restrict__ d3M,
                                        float* csum) {
    const int wv = t >> 6, lane = t & 63;
    const int gbase = wv * 640;
    const int cA = gbase >> 10;
    const int bnd = (cA + 1) << 10;
    const bool cross = (gbase + 640 > bnd);  // wave-uniform
    float s0[8] = {0.f, 0.f, 0.f, 0.f, 0.f, 0.f, 0.f, 0.f};
    float s1[8] = {0.f, 0.f, 0.f, 0.f, 0.f, 0.f, 0.f, 0.f};
#pragma unroll
    for (int j = 0; j < 5; ++j) {
        int gc = gbase + (j << 7);
        uint4 ma = d3M[gc + lane];
        uint4 mb = d3M[gc + 64 + lane];
        uint4 av0 = *(const uint4*)(sm + SM_H2 + ((ma.x & 0xffffu) << 4));
        uint4 bv0 = *(const uint4*)(sm + SM_H2 + ((ma.x >> 16) << 4));
        uint4 av1 = *(const uint4*)(sm + SM_H2 + ((mb.x & 0xffffu) << 4));
        uint4 bv1 = *(const uint4*)(sm + SM_H2 + ((mb.x >> 16) << 4));
        uint4 h0 = gate8(av0, bv0, make_uint2(ma.y, ma.z));
        uint4 h1v = gate8(av1, bv1, make_uint2(mb.y, mb.z));
        float pr8[8];
#pragma unroll
        for (int i = 0; i < 4; ++i) {
            __half2 pr = __hadd2(__builtin_bit_cast(__half2, (&h0.x)[i]),
                                 __builtin_bit_cast(__half2, (&h1v.x)[i]));
            pr8[2 * i] = __low2float(pr);
            pr8[2 * i + 1] = __high2float(pr);
        }
        if (gc < bnd) {  // wave-uniform per unrolled j, static indexing
#pragma unroll
            for (int r = 0; r < 8; ++r) s0[r] += pr8[r];
        } else {
#pragma unroll
            for (int r = 0; r < 8; ++r) s1[r] += pr8[r];
        }
    }
#pragma unroll
    for (int r = 0; r < 8; ++r) s0[r] = dpp_sum_f32(s0[r]);
    if (cross) {
#pragma unroll
        for (int r = 0; r < 8; ++r) s1[r] = dpp_sum_f32(s1[r]);
    }
    if (lane == 63) {
#pragma unroll
        for (int r = 0; r < 8; ++r) atomicAdd(&csum[cA * 8 + r], s0[r]);
        if (cross) {
#pragma unroll
            for (int r = 0; r < 8; ++r) atomicAdd(&csum[(cA + 1) * 8 + r], s1[r]);
        }
    }
}

// Fused: layers 1+2 fused, then layer 3 + group-sum. One block = 16 rows in
// two pipelined 8-row passes (256 blocks = exactly 1/CU, one round):
//  - all 16 row-loads of x issue at kernel top (rows 8-15 held in 8 VGPRs)
//  - xb for pass 2 is written DURING stage D of pass 1 (xb region dead then)
//    -> pass-2 stage-A HBM latency and cvt fully hidden (T14 split)
//  - per-CU prologue/metadata-preload paid once instead of twice.
__global__ __launch_bounds__(1024, 4) void fused_kernel(
    const float* __restrict__ x, const uint4* __restrict__ bcM1,
    const uint4* __restrict__ bcM2, const uint4* __restrict__ d3M,
    float* __restrict__ out) {
    extern __shared__ char sm[];
    uint4* xb = (uint4*)(sm + SM_XB);
    float* csum = (float*)(sm + SM_CSUM);

    const int t = threadIdx.x;
    const int rowbase = blockIdx.x << 4;  // 16 rows per block

    // Preload iter-0 index metadata for BC pass 1.
    uint4 m1a_n = bcM1[t];
    uint4 m1b_n = bcM1[t + 1024];

    // Stage A: issue all 16 row loads; stage rows 0-7 now, hold 8-15 in regs.
    const float* xp = x + (size_t)rowbase * D0 + t;
    float x2r[8];
#pragma unroll
    for (int i = 0; i < 8; ++i) x2r[i] = xp[(size_t)(8 + i) * D0];
    {
        uint4 v;
#pragma unroll
        for (int i = 0; i < 4; ++i) {
            float va = xp[(size_t)(2 * i) * D0];
            float vb = xp[(size_t)(2 * i + 1) * D0];
            (&v.x)[i] = __builtin_bit_cast(uint32_t, __floats2half2_rn(va, vb));
        }
        xb[t] = v;
    }
    if (t < 80) csum[t] = 0.f;
    __syncthreads();

    // ---- pass 1 (rows 0-7) ----
    stage_bc(sm, t, bcM1, bcM2, m1a_n, m1b_n);
    __syncthreads();  // h2 ready; all xb reads done -> xb region now dead

    // Stage A for pass 2: cvt held regs, write xb (overlaps with stage D).
    {
        uint4 v;
#pragma unroll
        for (int i = 0; i < 4; ++i)
            (&v.x)[i] = __builtin_bit_cast(
                uint32_t, __floats2half2_rn(x2r[2 * i], x2r[2 * i + 1]));
        xb[t] = v;
    }
    // Preload iter-0 metadata for BC pass 2 (L2-warm, hidden under stage D).
    m1a_n = bcM1[t];
    m1b_n = bcM1[t + 1024];

    stage_d(sm, t, d3M, csum);
    __syncthreads();  // csum ready; h2 reads done; xb(pass2) writes visible

    if (t < 80) {
        int c = t >> 3, r = t & 7;
        out[(size_t)(rowbase + r) * 10 + c] = csum[t] * (1.0f / 30.0f);
        csum[t] = 0.f;  // reset for pass 2 (visible after post-BC2 barrier)
    }

    // ---- pass 2 (rows 8-15) ----
    stage_bc(sm, t, bcM1, bcM2, m1a_n, m1b_n);
    __syncthreads();  // h2(pass2) ready; csum reset visible

    stage_d(sm, t, d3M, csum);
    __syncthreads();

    if (t < 80) {
        int c = t >> 3, r = t & 7;
        out[(size_t)(rowbase + 8 + r) * 10 + c] = csum[t] * (1.0f / 30.0f);
    }
}

extern "C" void kernel_launch(void* const* d_in, const int* in_sizes, int n_in,
                              void* d_out, int out_size, void* d_ws, size_t ws_size,
                              hipStream_t stream) {
    const float* x = (const float*)d_in[0];
    const float* w1 = (const float*)d_in[1];
    const float* w2 = (const float*)d_in[2];
    const float* w3 = (const float*)d_in[3];
    const int* ia1 = (const int*)d_in[4];
    const int* ib1 = (const int*)d_in[5];
    const int* ia2 = (const int*)d_in[6];
    const int* ib2 = (const int*)d_in[7];
    const int* ia3 = (const int*)d_in[8];
    const int* ib3 = (const int*)d_in[9];
    float* out = (float*)d_out;

    // Workspace: bcM1 128K | bcM2 128K | d3M 160K (all 16B-aligned).
    char* p = (char*)d_ws;
    uint4* bcM1 = (uint4*)p;    p += (size_t)D2 * 16;
    uint4* bcM2 = (uint4*)p;    p += (size_t)D2 * 16;
    uint4* d3M = (uint4*)p;

    // >64KB dynamic LDS opt-in (host-side; graph-capture safe). 144.3 KB
    // fits the 160 KB/CU pool.
    hipFuncSetAttribute(reinterpret_cast<const void*>(fused_kernel),
                        hipFuncAttributeMaxDynamicSharedMemorySize, SM_BYTES);

    prep_kernel<<<PREP_TOTAL / 256, 256, 0, stream>>>(
        w1, w2, w3, ia1, ib1, ia2, ib2, ia3, ib3, bcM1, bcM2, d3M);
    fused_kernel<<<B_ROWS / 16, 1024, SM_BYTES, stream>>>(x, bcM1, bcM2, d3M, out);
}